// Round 13
// baseline (1076.118 us; speedup 1.0000x reference)
//
#include <hip/hip_runtime.h>
#include <hip/hip_bf16.h>
#include <math.h>

#define B_ 8192
#define X_ 512
#define H_ 256
#define Z_ 64
#define L_ 16
#define W_ 32
#define G3_ 768

#define STDF 1.0025031276057952f
#define CC 0.9189385332046727f

typedef _Float16 f16x8 __attribute__((ext_vector_type(8)));
typedef float f32x4 __attribute__((ext_vector_type(4)));

__device__ __forceinline__ float sigm(float x) { return 1.0f / (1.0f + expf(-x)); }
__device__ __forceinline__ float logsig(float u) {
    return (u > 0.0f) ? -log1pf(expf(-u)) : (u - log1pf(expf(u)));
}

#define GLOAD16(gsrc, ldst) \
    __builtin_amdgcn_global_load_lds((const __attribute__((address_space(1))) unsigned int*)(gsrc), \
                                     (__attribute__((address_space(3))) unsigned int*)(ldst), 16, 0, 0)

#define WAITV(N) asm volatile("s_waitcnt vmcnt(" #N ")" ::: "memory")
#define WAITV0() asm volatile("s_waitcnt vmcnt(0)" ::: "memory")
#define SBAR()  do { __builtin_amdgcn_sched_barrier(0); __builtin_amdgcn_s_barrier(); } while (0)
#define PRIO1() __builtin_amdgcn_s_setprio(1)
#define PRIO0() __builtin_amdgcn_s_setprio(0)

#define MFMA16(a, b, c) __builtin_amdgcn_mfma_f32_16x16x32_f16((a), (b), (c), 0, 0, 0)

// ------- fused GRU step, BM=128, 512 threads, grid 256 (2 blocks/CU) --------
// MODE 1: enc (t >= .5); MODE 2: dec (t > .5). KX = A2 inner dim.
template<int MODE, int KX, int FIRST>
__global__ __launch_bounds__(512) void gru_fused(
    const _Float16* __restrict__ A2,
    const _Float16* __restrict__ Wih,
    const float* __restrict__ bih,
    const _Float16* __restrict__ Whh,
    const float* __restrict__ bhh,
    const float* __restrict__ ec,
    const float* __restrict__ tcol,
    const float* __restrict__ eps,
    const _Float16* __restrict__ zh_in,
    float* __restrict__ z,
    _Float16* __restrict__ zh_out)
{
    constexpr int N1 = KX / 64;
    constexpr int NT = N1 + (FIRST ? 0 : 4);
    __shared__ char smem[2][(128 + 192) * 128];   // 80 KB

    const int tid  = threadIdx.x;
    const int wave = tid >> 6;
    const int lane = tid & 63;
    const int wr   = wave >> 1;          // 0..3: 32-row quarter
    const int wc   = wave & 1;           // 0..1: 32-col half per gate
    const int id   = blockIdx.x;
    const int xcd  = id & 7;
    const int wk   = id >> 3;            // 0..31
    const int bm   = (xcd * 8 + (wk >> 2)) * 128;
    const int h0   = (wk & 3) * 64;
    const int l15  = lane & 15;
    const int l4   = lane >> 4;

    f32x4 acc[2][6];
    f32x4 accN[2][2];
    #pragma unroll
    for (int a = 0; a < 2; ++a) {
        #pragma unroll
        for (int b = 0; b < 6; ++b) { f32x4 zz = {0.f,0.f,0.f,0.f}; acc[a][b] = zz; }
        #pragma unroll
        for (int b = 0; b < 2; ++b) { f32x4 zz = {0.f,0.f,0.f,0.f}; accN[a][b] = zz; }
    }

    auto stage = [&](int s, int pb) {
        char* As = smem[pb];
        char* Ws = smem[pb] + 128 * 128;
        const _Float16* srcA;
        const _Float16* srcW;
        int KA, k0;
        if (s < N1) { srcA = A2;    srcW = Wih; KA = KX;  k0 = s * 64; }
        else        { srcA = zh_in; srcW = Whh; KA = 256; k0 = (s - N1) * 64; }
        #pragma unroll
        for (int q = 0; q < 2; ++q) {
            int f   = q * 8192 + tid * 16;
            int row = f >> 7;
            int c   = ((f >> 4) & 7) ^ (row & 7);
            GLOAD16(srcA + (long)(bm + row) * KA + k0 + c * 8, As + f);
        }
        #pragma unroll
        for (int q = 0; q < 3; ++q) {
            int f   = q * 8192 + tid * 16;
            int rr  = f >> 7;
            int c   = ((f >> 4) & 7) ^ (rr & 7);
            int srow = (rr >> 6) * 256 + h0 + (rr & 63);
            GLOAD16(srcW + (long)srow * KA + k0 + c * 8, Ws + f);
        }
    };

    stage(0, 0);
    for (int s = 0; s < NT; ++s) {
        int pb = s & 1;
        if (s + 1 < NT) { stage(s + 1, pb ^ 1); WAITV(5); }
        else WAITV0();
        SBAR();
        char* As = smem[pb];
        char* Ws = smem[pb] + 128 * 128;
        bool p1 = (s < N1);
        PRIO1();
        #pragma unroll
        for (int ks = 0; ks < 2; ++ks) {
            f16x8 af[2], bf[6];
            #pragma unroll
            for (int mi = 0; mi < 2; ++mi) {
                int row = wr * 32 + mi * 16 + l15;
                int c   = (ks * 4 + l4) ^ (row & 7);
                af[mi] = *(const f16x8*)(As + row * 128 + c * 16);
            }
            #pragma unroll
            for (int ni = 0; ni < 6; ++ni) {
                int rr = (ni >> 1) * 64 + wc * 32 + (ni & 1) * 16 + l15;
                int c  = (ks * 4 + l4) ^ (rr & 7);
                bf[ni] = *(const f16x8*)(Ws + rr * 128 + c * 16);
            }
            if (p1) {
                #pragma unroll
                for (int mi = 0; mi < 2; ++mi) {
                    #pragma unroll
                    for (int ni = 0; ni < 4; ++ni)
                        acc[mi][ni] = MFMA16(af[mi], bf[ni], acc[mi][ni]);
                    #pragma unroll
                    for (int ni = 4; ni < 6; ++ni)
                        accN[mi][ni - 4] = MFMA16(af[mi], bf[ni], accN[mi][ni - 4]);
                }
            } else {
                #pragma unroll
                for (int mi = 0; mi < 2; ++mi)
                    #pragma unroll
                    for (int ni = 0; ni < 6; ++ni)
                        acc[mi][ni] = MFMA16(af[mi], bf[ni], acc[mi][ni]);
            }
        }
        PRIO0();
        SBAR();
    }

    #pragma unroll
    for (int mi = 0; mi < 2; ++mi)
        #pragma unroll
        for (int r = 0; r < 4; ++r) {
            int grow = bm + wr * 32 + mi * 16 + l4 * 4 + r;
            float tv = tcol[(long)grow * L_];
            float ext = (MODE == 1) ? (tv >= 0.5f ? 1.0f : 0.0f)
                                    : (tv >  0.5f ? 1.0f : 0.0f);
            #pragma unroll
            for (int hb = 0; hb < 2; ++hb) {
                int h = h0 + wc * 32 + hb * 16 + l15;
                float rpre = acc[mi][hb][r]     + bih[h]       + bhh[h]       + ext * ec[h];
                float zpre = acc[mi][2 + hb][r] + bih[256 + h] + bhh[256 + h] + ext * ec[256 + h];
                float hn   = acc[mi][4 + hb][r] + bhh[512 + h];
                float in_  = accN[mi][hb][r]    + bih[512 + h] + ext * ec[512 + h];
                float rg = sigm(rpre);
                float zt = sigm(zpre);
                float n  = tanhf(in_ + rg * hn);
                long zi = (long)grow * 256 + h;
                float zold = FIRST ? 0.0f : z[zi];
                float v = (1.0f - zt) * n + zt * zold + STDF * eps[zi];
                z[zi] = v;
                zh_out[zi] = (_Float16)v;
            }
        }
}

// ------- predict head K=512 (first cell), pipelined BM=32 -------------------
__global__ __launch_bounds__(256) void predict_head512(
    const _Float16* __restrict__ A,
    const _Float16* __restrict__ Wd,     // [256][512]
    const float* __restrict__ bd,
    const float* __restrict__ wo,
    const float* __restrict__ bo,
    float* __restrict__ out, int ostride)
{
    constexpr int K = 512;
    constexpr int NT = K / 64;
    __shared__ char smem[2][(32 + 256) * 128];
    __shared__ float part[32][4];

    const int tid  = threadIdx.x;
    const int wave = tid >> 6;
    const int lane = tid & 63;
    const int bm   = blockIdx.x * 32;
    const int l15  = lane & 15;
    const int l4   = lane >> 4;

    f32x4 acc[2][4];
    #pragma unroll
    for (int a = 0; a < 2; ++a)
        #pragma unroll
        for (int b = 0; b < 4; ++b) { f32x4 zz = {0.f,0.f,0.f,0.f}; acc[a][b] = zz; }

    auto stage = [&](int s, int pb) {
        char* As = smem[pb];
        char* Ws = smem[pb] + 32 * 128;
        int k0 = s * 64;
        {
            int o   = wave * 1024 + lane * 16;
            int row = o >> 7;
            int c   = ((o >> 4) & 7) ^ (row & 7);
            GLOAD16(A + (long)(bm + row) * K + k0 + c * 8, As + wave * 1024);
        }
        #pragma unroll
        for (int it = 0; it < 8; ++it) {
            int q   = it * 4 + wave;
            int o   = q * 1024 + lane * 16;
            int row = o >> 7;
            int c   = ((o >> 4) & 7) ^ (row & 7);
            GLOAD16(Wd + (long)row * K + k0 + c * 8, Ws + q * 1024);
        }
    };

    stage(0, 0);
    for (int s = 0; s < NT; ++s) {
        int pb = s & 1;
        if (s + 1 < NT) { stage(s + 1, pb ^ 1); WAITV(9); }
        else WAITV0();
        SBAR();
        char* As = smem[pb];
        char* Ws = smem[pb] + 32 * 128;
        #pragma unroll
        for (int ks = 0; ks < 2; ++ks) {
            f16x8 af[2], bf[4];
            #pragma unroll
            for (int mi = 0; mi < 2; ++mi) {
                int row = mi * 16 + l15;
                int c   = (ks * 4 + l4) ^ (row & 7);
                af[mi] = *(const f16x8*)(As + row * 128 + c * 16);
            }
            #pragma unroll
            for (int ni = 0; ni < 4; ++ni) {
                int row = wave * 64 + ni * 16 + l15;
                int c   = (ks * 4 + l4) ^ (row & 7);
                bf[ni] = *(const f16x8*)(Ws + row * 128 + c * 16);
            }
            #pragma unroll
            for (int mi = 0; mi < 2; ++mi)
                #pragma unroll
                for (int ni = 0; ni < 4; ++ni)
                    acc[mi][ni] = MFMA16(af[mi], bf[ni], acc[mi][ni]);
        }
        SBAR();
    }

    float bdv[4], wov[4];
    #pragma unroll
    for (int ni = 0; ni < 4; ++ni) {
        int col = wave * 64 + ni * 16 + l15;
        bdv[ni] = bd[col];
        wov[ni] = wo[col];
    }
    #pragma unroll
    for (int mi = 0; mi < 2; ++mi)
        #pragma unroll
        for (int r = 0; r < 4; ++r) {
            float s = 0.0f;
            #pragma unroll
            for (int ni = 0; ni < 4; ++ni) {
                float v = fmaxf(acc[mi][ni][r] + bdv[ni], 0.0f);
                s = fmaf(v, wov[ni], s);
            }
            #pragma unroll
            for (int off = 1; off < 16; off <<= 1) s += __shfl_xor(s, off, 16);
            if (l15 == 0) part[mi * 16 + l4 * 4 + r][wave] = s;
        }
    __syncthreads();
    if (tid < 32) {
        float u = part[tid][0] + part[tid][1] + part[tid][2] + part[tid][3] + bo[0];
        out[(long)(bm + tid) * ostride] = sigm(u);
    }
}

// ------- predict head K=256: full-W LDS, single stage -----------------------
__global__ __launch_bounds__(256) void predict_fast(
    const _Float16* __restrict__ A,
    const _Float16* __restrict__ Wd,     // [256][256]
    const float* __restrict__ bd,
    const float* __restrict__ wo,
    const float* __restrict__ bo,
    float* __restrict__ out, int ostride)
{
    __shared__ char Wl[131072];
    __shared__ char Al[16384];
    __shared__ float part[32][4];

    const int tid  = threadIdx.x;
    const int wave = tid >> 6;
    const int lane = tid & 63;
    const int bm   = blockIdx.x * 32;
    const int l15  = lane & 15;
    const int l4   = lane >> 4;

    #pragma unroll
    for (int q = 0; q < 32; ++q) {
        int f   = q * 4096 + tid * 16;
        int kc  = f >> 15;
        int o   = f & 32767;
        int row = o >> 7;
        int c   = ((o >> 4) & 7) ^ (row & 7);
        GLOAD16(Wd + (long)row * 256 + kc * 64 + c * 8, Wl + f);
    }
    #pragma unroll
    for (int q = 0; q < 4; ++q) {
        int f   = q * 4096 + tid * 16;
        int kc  = f >> 12;
        int o   = f & 4095;
        int row = o >> 7;
        int c   = ((o >> 4) & 7) ^ (row & 7);
        GLOAD16(A + (long)(bm + row) * 256 + kc * 64 + c * 8, Al + f);
    }
    WAITV0();
    __syncthreads();

    f32x4 acc[2][4];
    #pragma unroll
    for (int a = 0; a < 2; ++a)
        #pragma unroll
        for (int b = 0; b < 4; ++b) { f32x4 zz = {0.f,0.f,0.f,0.f}; acc[a][b] = zz; }

    PRIO1();
    #pragma unroll
    for (int kc = 0; kc < 4; ++kc)
        #pragma unroll
        for (int ks = 0; ks < 2; ++ks) {
            f16x8 af[2], bf[4];
            #pragma unroll
            for (int mi = 0; mi < 2; ++mi) {
                int row = mi * 16 + l15;
                int c   = (ks * 4 + l4) ^ (row & 7);
                af[mi] = *(const f16x8*)(Al + kc * 4096 + row * 128 + c * 16);
            }
            #pragma unroll
            for (int ni = 0; ni < 4; ++ni) {
                int row = wave * 64 + ni * 16 + l15;
                int c   = (ks * 4 + l4) ^ (row & 7);
                bf[ni] = *(const f16x8*)(Wl + kc * 32768 + row * 128 + c * 16);
            }
            #pragma unroll
            for (int mi = 0; mi < 2; ++mi)
                #pragma unroll
                for (int ni = 0; ni < 4; ++ni)
                    acc[mi][ni] = MFMA16(af[mi], bf[ni], acc[mi][ni]);
        }
    PRIO0();

    float bdv[4], wov[4];
    #pragma unroll
    for (int ni = 0; ni < 4; ++ni) {
        int col = wave * 64 + ni * 16 + l15;
        bdv[ni] = bd[col];
        wov[ni] = wo[col];
    }
    #pragma unroll
    for (int mi = 0; mi < 2; ++mi)
        #pragma unroll
        for (int r = 0; r < 4; ++r) {
            float s = 0.0f;
            #pragma unroll
            for (int ni = 0; ni < 4; ++ni) {
                float v = fmaxf(acc[mi][ni][r] + bdv[ni], 0.0f);
                s = fmaf(v, wov[ni], s);
            }
            #pragma unroll
            for (int off = 1; off < 16; off <<= 1) s += __shfl_xor(s, off, 16);
            if (l15 == 0) part[mi * 16 + l4 * 4 + r][wave] = s;
        }
    __syncthreads();
    if (tid < 32) {
        float u = part[tid][0] + part[tid][1] + part[tid][2] + part[tid][3] + bo[0];
        out[(long)(bm + tid) * ostride] = sigm(u);
    }
}

// ------- decoder head+BCE: full-Wd LDS single stage, A direct from L2 -------
__global__ __launch_bounds__(256) void dec_head_bce_fast(
    const _Float16* __restrict__ A,      // zh [B][256]
    const _Float16* __restrict__ Wd,     // [256][256]
    const float* __restrict__ bd,
    const _Float16* __restrict__ Wo,     // [32][256]
    const float* __restrict__ bo,
    const float* __restrict__ wt,        // [B][32]
    float* __restrict__ bacc)
{
    __shared__ char Wl[131072];
    __shared__ _Float16 ds[32 * 264];
    __shared__ float part[32][2];

    const int tid  = threadIdx.x;
    const int wave = tid >> 6;
    const int lane = tid & 63;
    const int bm   = blockIdx.x * 32;
    const int l15  = lane & 15;
    const int l4   = lane >> 4;

    #pragma unroll
    for (int q = 0; q < 32; ++q) {
        int f   = q * 4096 + tid * 16;
        int kc  = f >> 15;
        int o   = f & 32767;
        int row = o >> 7;
        int c   = ((o >> 4) & 7) ^ (row & 7);
        GLOAD16(Wd + (long)row * 256 + kc * 64 + c * 8, Wl + f);
    }
    f16x8 afr[8];
    #pragma unroll
    for (int kc = 0; kc < 4; ++kc)
        #pragma unroll
        for (int mi = 0; mi < 2; ++mi) {
            int row = mi * 16 + l15;
            afr[kc * 2 + mi] = *(const f16x8*)(A + (long)(bm + row) * 256 + kc * 64 + l4 * 8);
        }

    f32x4 acc[2][4];
    #pragma unroll
    for (int a = 0; a < 2; ++a)
        #pragma unroll
        for (int b = 0; b < 4; ++b) { f32x4 zz = {0.f,0.f,0.f,0.f}; acc[a][b] = zz; }

    WAITV0();
    __syncthreads();

    PRIO1();
    #pragma unroll
    for (int kc = 0; kc < 4; ++kc) {
        f16x8 bf[4];
        #pragma unroll
        for (int ni = 0; ni < 4; ++ni) {
            int row = wave * 64 + ni * 16 + l15;
            int c   = (0 * 4 + l4) ^ (row & 7);
            bf[ni] = *(const f16x8*)(Wl + kc * 32768 + row * 128 + c * 16);
        }
        #pragma unroll
        for (int mi = 0; mi < 2; ++mi)
            #pragma unroll
            for (int ni = 0; ni < 4; ++ni)
                acc[mi][ni] = MFMA16(afr[kc * 2 + mi], bf[ni], acc[mi][ni]);
    }
    PRIO0();
    #pragma unroll
    for (int kc = 0; kc < 4; ++kc)
        #pragma unroll
        for (int mi = 0; mi < 2; ++mi) {
            int row = mi * 16 + l15;
            afr[kc * 2 + mi] = *(const f16x8*)(A + (long)(bm + row) * 256 + kc * 64 + 32 + l4 * 8);
        }
    PRIO1();
    #pragma unroll
    for (int kc = 0; kc < 4; ++kc) {
        f16x8 bf[4];
        #pragma unroll
        for (int ni = 0; ni < 4; ++ni) {
            int row = wave * 64 + ni * 16 + l15;
            int c   = (1 * 4 + l4) ^ (row & 7);
            bf[ni] = *(const f16x8*)(Wl + kc * 32768 + row * 128 + c * 16);
        }
        #pragma unroll
        for (int mi = 0; mi < 2; ++mi)
            #pragma unroll
            for (int ni = 0; ni < 4; ++ni)
                acc[mi][ni] = MFMA16(afr[kc * 2 + mi], bf[ni], acc[mi][ni]);
    }
    PRIO0();

    #pragma unroll
    for (int mi = 0; mi < 2; ++mi)
        #pragma unroll
        for (int r = 0; r < 4; ++r) {
            int row = mi * 16 + l4 * 4 + r;
            #pragma unroll
            for (int ni = 0; ni < 4; ++ni) {
                int col = wave * 64 + ni * 16 + l15;
                ds[row * 264 + col] = (_Float16)fmaxf(acc[mi][ni][r] + bd[col], 0.0f);
            }
        }
    __syncthreads();

    const int rh = wave >> 1;
    const int ch = wave & 1;
    f32x4 acc2 = {0.f, 0.f, 0.f, 0.f};
    #pragma unroll
    for (int k = 0; k < 8; ++k) {
        f16x8 bf2 = *(const f16x8*)(Wo + (long)(ch * 16 + l15) * 256 + k * 32 + l4 * 8);
        f16x8 af  = *(const f16x8*)(ds + (rh * 16 + l15) * 264 + k * 32 + l4 * 8);
        acc2 = MFMA16(af, bf2, acc2);
    }

    #pragma unroll
    for (int r = 0; r < 4; ++r) {
        int row = rh * 16 + l4 * 4 + r;
        int w = ch * 16 + l15;
        float u = acc2[r] + bo[w];
        float logp   = fmaxf(logsig(u),  -100.0f);
        float log1mp = fmaxf(logsig(-u), -100.0f);
        float wk = wt[(long)(bm + row) * W_ + w];
        float s = -(wk * logp + (1.0f - wk) * log1mp);
        #pragma unroll
        for (int off = 1; off < 16; off <<= 1) s += __shfl_xor(s, off, 16);
        if (l15 == 0) part[row][ch] = s;
    }
    __syncthreads();
    if (tid < 32) bacc[bm + tid] += part[tid][0] + part[tid][1];
}

// ------- latent: full-Wml GEMM + softplus/sample/lq/lpz, fused --------------
__global__ __launch_bounds__(256) void latent_fused(
    const _Float16* __restrict__ A,      // zfin f16 [B][256]
    const _Float16* __restrict__ Wml,    // [128][256] (mu|lv rows)
    const float* __restrict__ bml,       // [128]
    const float* __restrict__ seps,
    _Float16* __restrict__ lath,
    float* __restrict__ lq, float* __restrict__ lpz)
{
    __shared__ char Wl[65536];
    __shared__ char Al[16384];
    __shared__ float muv[32][129];

    const int tid  = threadIdx.x;
    const int wave = tid >> 6;
    const int lane = tid & 63;
    const int bm   = blockIdx.x * 32;
    const int l15  = lane & 15;
    const int l4   = lane >> 4;

    #pragma unroll
    for (int q = 0; q < 16; ++q) {
        int f   = q * 4096 + tid * 16;
        int kc  = f >> 14;
        int o   = f & 16383;
        int row = o >> 7;
        int c   = ((o >> 4) & 7) ^ (row & 7);
        GLOAD16(Wml + (long)row * 256 + kc * 64 + c * 8, Wl + f);
    }
    #pragma unroll
    for (int q = 0; q < 4; ++q) {
        int f   = q * 4096 + tid * 16;
        int kc  = f >> 12;
        int o   = f & 4095;
        int row = o >> 7;
        int c   = ((o >> 4) & 7) ^ (row & 7);
        GLOAD16(A + (long)(bm + row) * 256 + kc * 64 + c * 8, Al + f);
    }
    WAITV0();
    __syncthreads();

    f32x4 acc[2][2];
    #pragma unroll
    for (int a = 0; a < 2; ++a)
        #pragma unroll
        for (int b = 0; b < 2; ++b) { f32x4 zz = {0.f,0.f,0.f,0.f}; acc[a][b] = zz; }

    #pragma unroll
    for (int kc = 0; kc < 4; ++kc)
        #pragma unroll
        for (int ks = 0; ks < 2; ++ks) {
            f16x8 af[2], bf[2];
            #pragma unroll
            for (int mi = 0; mi < 2; ++mi) {
                int row = mi * 16 + l15;
                int c   = (ks * 4 + l4) ^ (row & 7);
                af[mi] = *(const f16x8*)(Al + kc * 4096 + row * 128 + c * 16);
            }
            #pragma unroll
            for (int ni = 0; ni < 2; ++ni) {
                int row = wave * 32 + ni * 16 + l15;
                int c   = (ks * 4 + l4) ^ (row & 7);
                bf[ni] = *(const f16x8*)(Wl + kc * 16384 + row * 128 + c * 16);
            }
            #pragma unroll
            for (int mi = 0; mi < 2; ++mi)
                #pragma unroll
                for (int ni = 0; ni < 2; ++ni)
                    acc[mi][ni] = MFMA16(af[mi], bf[ni], acc[mi][ni]);
        }

    #pragma unroll
    for (int mi = 0; mi < 2; ++mi)
        #pragma unroll
        for (int r = 0; r < 4; ++r) {
            int row = mi * 16 + l4 * 4 + r;
            #pragma unroll
            for (int ni = 0; ni < 2; ++ni) {
                int col = wave * 32 + ni * 16 + l15;
                muv[row][col] = acc[mi][ni][r] + bml[col];
            }
        }
    __syncthreads();

    int rsub = lane >> 3;
    int row  = wave * 8 + rsub;
    int zlo  = lane & 7;
    float lpz_c = 0.0f, lq_c = 0.0f;
    #pragma unroll
    for (int j = 0; j < 8; ++j) {
        int zc = zlo * 8 + j;
        float mu = muv[row][zc];
        float sp = muv[row][64 + zc];
        float lv = (sp > 0.0f) ? (sp + log1pf(expf(-sp))) : log1pf(expf(sp));
        float e  = seps[(long)(bm + row) * Z_ + zc];
        float lat = mu + expf(0.5f * lv) * e;
        lath[(long)(bm + row) * Z_ + zc] = (_Float16)lat;
        lpz_c += -CC - 0.5f * lat * lat;
        float d = lat - mu;
        lq_c += -CC - 0.5f * lv - d * d / (2.0f * expf(lv));
    }
    #pragma unroll
    for (int off = 1; off < 8; off <<= 1) {
        lpz_c += __shfl_xor(lpz_c, off, 8);
        lq_c  += __shfl_xor(lq_c, off, 8);
    }
    if (zlo == 0) { lpz[bm + row] = lpz_c; lq[bm + row] = lq_c; }
}

// ------- recon GEMM (BM=128, BN=128) + log_p_x epilogue (atomic) ------------
__global__ __launch_bounds__(256) void recon_logpx_gemm(
    const _Float16* __restrict__ A,      // zh [B][256]
    const _Float16* __restrict__ Wt,     // [512][256]
    const float* __restrict__ bias,      // [512]
    const float* __restrict__ x,         // [B][512]
    float* __restrict__ lpx)
{
    constexpr int K = 256;
    constexpr int NT = 4;
    __shared__ char smem[2][(128 + 128) * 128];
    __shared__ float part[128][2];

    const int tid  = threadIdx.x;
    const int wave = tid >> 6;
    const int lane = tid & 63;
    const int wr   = wave >> 1;
    const int wc   = wave & 1;
    const int bm   = blockIdx.y * 128;
    const int bn   = blockIdx.x * 128;
    const int l15  = lane & 15;
    const int l4   = lane >> 4;

    f32x4 acc[4][4];
    #pragma unroll
    for (int a = 0; a < 4; ++a)
        #pragma unroll
        for (int b = 0; b < 4; ++b) { f32x4 zz = {0.f,0.f,0.f,0.f}; acc[a][b] = zz; }

    auto stage = [&](int s, int pb) {
        char* As = smem[pb];
        char* Ws = smem[pb] + 128 * 128;
        int k0 = s * 64;
        #pragma unroll
        for (int it = 0; it < 4; ++it) {
            int q   = it * 4 + wave;
            int o   = q * 1024 + lane * 16;
            int row = o >> 7;
            int c   = ((o >> 4) & 7) ^ (row & 7);
            GLOAD16(A + (long)(bm + row) * K + k0 + c * 8, As + q * 1024);
        }
        #pragma unroll
        for (int it = 0; it < 4; ++it) {
            int q   = it * 4 + wave;
            int o   = q * 1024 + lane * 16;
            int row = o >> 7;
            int c   = ((o >> 4) & 7) ^ (row & 7);
            GLOAD16(Wt + (long)(bn + row) * K + k0 + c * 8, Ws + q * 1024);
        }
    };

    stage(0, 0);
    for (int s = 0; s < NT; ++s) {
        int pb = s & 1;
        if (s + 1 < NT) { stage(s + 1, pb ^ 1); WAITV(8); }
        else WAITV0();
        SBAR();
        char* As = smem[pb];
        char* Ws = smem[pb] + 128 * 128;
        #pragma unroll
        for (int ks = 0; ks < 2; ++ks) {
            f16x8 af[4], bf[4];
            #pragma unroll
            for (int mi = 0; mi < 4; ++mi) {
                int row = wr * 64 + mi * 16 + l15;
                int c   = (ks * 4 + l4) ^ (row & 7);
                af[mi] = *(const f16x8*)(As + row * 128 + c * 16);
            }
            #pragma unroll
            for (int ni = 0; ni < 4; ++ni) {
                int row = wc * 64 + ni * 16 + l15;
                int c   = (ks * 4 + l4) ^ (row & 7);
                bf[ni] = *(const f16x8*)(Ws + row * 128 + c * 16);
            }
            #pragma unroll
            for (int mi = 0; mi < 4; ++mi)
                #pragma unroll
                for (int ni = 0; ni < 4; ++ni)
                    acc[mi][ni] = MFMA16(af[mi], bf[ni], acc[mi][ni]);
        }
        SBAR();
    }

    #pragma unroll
    for (int mi = 0; mi < 4; ++mi)
        #pragma unroll
        for (int r = 0; r < 4; ++r) {
            int grow = bm + wr * 64 + mi * 16 + l4 * 4 + r;
            float s = 0.0f;
            #pragma unroll
            for (int ni = 0; ni < 4; ++ni) {
                int gcol = bn + wc * 64 + ni * 16 + l15;
                float u = acc[mi][ni][r] + bias[gcol];
                s = fmaf(x[(long)grow * X_ + gcol], logsig(u), s);
            }
            #pragma unroll
            for (int off = 1; off < 16; off <<= 1) s += __shfl_xor(s, off, 16);
            if (l15 == 0) part[wr * 64 + mi * 16 + l4 * 4 + r][wc] = s;
        }
    __syncthreads();
    if (tid < 128) atomicAdd(&lpx[bm + tid], part[tid][0] + part[tid][1]);
}

// ---------------- fused contiguous f32->f16 conversions ---------------------
struct ConvJobs {
    const float* s[10];
    _Float16* d[10];
};
__device__ __constant__ const long CJ_CNT[10] = {
    (long)B_ * X_, (long)H_ * X_, (long)L_ * G3_ * H_, (long)L_ * H_ * H_,
    (long)L_ * G3_ * H_, (long)L_ * H_ * H_, (long)L_ * W_ * H_,
    (long)X_ * H_, (long)Z_ * H_, (long)Z_ * H_
};
#define CJ_TOTAL 13008896L

__global__ __launch_bounds__(256) void conv_multi(ConvJobs J)
{
    long i8 = ((long)blockIdx.x * 256 + threadIdx.x) * 8;
    if (i8 >= CJ_TOTAL) return;
    long rem = i8; int j = 0;
    #pragma unroll
    for (int k = 0; k < 9; ++k)
        if (rem >= CJ_CNT[k]) { rem -= CJ_CNT[k]; ++j; } else break;
    const float* s = J.s[j] + rem;
    f16x8 o;
    #pragma unroll
    for (int q = 0; q < 8; ++q) o[q] = (_Float16)s[q];
    *(f16x8*)(J.d[j] + rem) = o;
}

// strided convs + extracts + bias-stack + wtrans (+zero bacc/lpx), one kernel
__global__ __launch_bounds__(256) void prep_misc(
    const float* __restrict__ eWih, _Float16* __restrict__ eWihh,
    const float* __restrict__ dWih, _Float16* __restrict__ dWihh,
    const float* __restrict__ workers, float* __restrict__ wt,
    float* __restrict__ bacc, float* __restrict__ lpx,
    float* __restrict__ eWihc, float* __restrict__ dWihc,
    const float* __restrict__ bmu, const float* __restrict__ blv,
    float* __restrict__ bml)
{
    int blk = blockIdx.x;
    int tid = threadIdx.x;
    if (blk < 3072) {                       // eWih: [12288][513] -> [12288][512] f16
        long i = ((long)blk * 256 + tid) * 8;
        long r = i >> 9, k = i & 511;
        const float* s = eWih + r * 513 + k;
        f16x8 o;
        #pragma unroll
        for (int q = 0; q < 8; ++q) o[q] = (_Float16)s[q];
        *(f16x8*)(eWihh + i) = o;
    } else if (blk < 3456) {                // dWih: [12288][65] -> [12288][64] f16
        long i = ((long)(blk - 3072) * 256 + tid) * 8;
        long r = i >> 6, k = i & 63;
        const float* s = dWih + r * 65 + k;
        f16x8 o;
        #pragma unroll
        for (int q = 0; q < 8; ++q) o[q] = (_Float16)s[q];
        *(f16x8*)(dWihh + i) = o;
    } else if (blk < 4480) {                // wtrans + zero bacc/lpx
        long idx = (long)(blk - 3456) * 256 + tid;
        int w = idx & 31;
        long b = idx >> 5;
        const float* src = workers + (w * (long)B_ + b) * L_;
        #pragma unroll
        for (int l = 0; l < L_; ++l)
            wt[((long)l * B_ + b) * W_ + w] = src[l];
        if (w == 0) { bacc[b] = 0.0f; lpx[b] = 0.0f; }
    } else if (blk < 4528) {                // extract eWih col 512
        int i = (blk - 4480) * 256 + tid;
        if (i < L_ * G3_) eWihc[i] = eWih[(long)i * 513 + 512];
    } else if (blk < 4576) {                // extract dWih col 64
        int i = (blk - 4528) * 256 + tid;
        if (i < L_ * G3_) dWihc[i] = dWih[(long)i * 65 + 64];
    } else {                                // stack bias
        if (tid < 128) bml[tid] = (tid < 64) ? bmu[tid] : blv[tid - 64];
    }
}

// ---------------- KL term ---------------------------------------------------
__global__ __launch_bounds__(256) void kl_kernel(
    const float* __restrict__ tmat, const float* __restrict__ workers,
    float* __restrict__ lkl)
{
    int b = blockIdx.x * 256 + threadIdx.x;
    float wb[L_];
    #pragma unroll
    for (int l = 0; l < L_; ++l) wb[l] = 0.0f;
    for (int w = 0; w < W_; ++w) {
        const float* p = workers + ((long)w * B_ + b) * L_;
        #pragma unroll
        for (int l = 0; l < L_; ++l) wb[l] += p[l];
    }
    float s = 0.0f;
    #pragma unroll
    for (int l = 0; l < L_; ++l) {
        float wbar = wb[l] * (1.0f / 32.0f);
        float tv = tmat[(long)b * L_ + l];
        s += tv * (logf(tv + 1e-6f) - logf(wbar + 1e-6f));
    }
    lkl[b] = s;
}

// ---------------- final reduction ------------------------------------------
__global__ __launch_bounds__(1024) void final_reduce(
    const float* __restrict__ lq, const float* __restrict__ lpz,
    const float* __restrict__ bacc, const float* __restrict__ lpx,
    const float* __restrict__ lkl, float* __restrict__ out)
{
    __shared__ float red[16];
    float s = 0.0f;
    for (int b = threadIdx.x; b < B_; b += 1024)
        s += lq[b] - lpz[b] + bacc[b] - lpx[b] + lkl[b];
    #pragma unroll
    for (int off = 32; off; off >>= 1) s += __shfl_down(s, off);
    int wave = threadIdx.x >> 6, lane = threadIdx.x & 63;
    if (lane == 0) red[wave] = s;
    __syncthreads();
    if (threadIdx.x == 0) {
        float t = 0.0f;
        for (int i = 0; i < 16; ++i) t += red[i];
        out[0] = t / (float)B_;
    }
}

extern "C" void kernel_launch(void* const* d_in, const int* in_sizes, int n_in,
                              void* d_out, int out_size, void* d_ws, size_t ws_size,
                              hipStream_t stream)
{
    const float* x       = (const float*)d_in[0];
    const float* workers = (const float*)d_in[1];
    const float* Wf1     = (const float*)d_in[2];
    const float* bf1     = (const float*)d_in[3];
    const float* Wf2     = (const float*)d_in[4];
    const float* bf2     = (const float*)d_in[5];
    const float* eWih    = (const float*)d_in[6];
    const float* eWhh    = (const float*)d_in[7];
    const float* ebih    = (const float*)d_in[8];
    const float* ebhh    = (const float*)d_in[9];
    const float* eWd     = (const float*)d_in[10];
    const float* ebd     = (const float*)d_in[11];
    const float* eWo     = (const float*)d_in[12];
    const float* ebo     = (const float*)d_in[13];
    const float* Wmu     = (const float*)d_in[14];
    const float* bmu     = (const float*)d_in[15];
    const float* Wlv     = (const float*)d_in[16];
    const float* blv     = (const float*)d_in[17];
    const float* dWih    = (const float*)d_in[18];
    const float* dWhh    = (const float*)d_in[19];
    const float* dbih    = (const float*)d_in[20];
    const float* dbhh    = (const float*)d_in[21];
    const float* dWd     = (const float*)d_in[22];
    const float* dbd     = (const float*)d_in[23];
    const float* dWo     = (const float*)d_in[24];
    const float* dbo     = (const float*)d_in[25];
    const float* Wr      = (const float*)d_in[26];
    const float* br      = (const float*)d_in[27];
    const float* enc_eps = (const float*)d_in[28];
    const float* samp_eps= (const float*)d_in[29];
    const float* dec_eps = (const float*)d_in[30];

    float* t    = (float*)d_out;
    float* loss = t + (long)B_ * L_;

    char* p = (char*)d_ws;
    auto alloc = [&](size_t bytes) {
        char* r = p;
        p += (bytes + 255) & ~(size_t)255;
        return r;
    };
    _Float16* xh    = (_Float16*)alloc((size_t)B_ * X_ * 2);
    _Float16* zb0   = (_Float16*)alloc((size_t)B_ * H_ * 2);
    _Float16* zb1   = (_Float16*)alloc((size_t)B_ * H_ * 2);
    _Float16* lath  = (_Float16*)alloc((size_t)B_ * Z_ * 2);
    _Float16* Wf1h  = (_Float16*)alloc((size_t)H_ * X_ * 2);
    _Float16* eWihh = (_Float16*)alloc((size_t)L_ * G3_ * X_ * 2);
    _Float16* eWhhh = (_Float16*)alloc((size_t)L_ * G3_ * H_ * 2);
    _Float16* eWdh  = (_Float16*)alloc((size_t)L_ * H_ * H_ * 2);
    _Float16* dWihh = (_Float16*)alloc((size_t)L_ * G3_ * Z_ * 2);
    _Float16* dWhhh = (_Float16*)alloc((size_t)L_ * G3_ * H_ * 2);
    _Float16* dWdh  = (_Float16*)alloc((size_t)L_ * H_ * H_ * 2);
    _Float16* dWoh  = (_Float16*)alloc((size_t)L_ * W_ * H_ * 2);
    _Float16* Wrh   = (_Float16*)alloc((size_t)X_ * H_ * 2);
    _Float16* Wmlh  = (_Float16*)alloc((size_t)128 * H_ * 2);
    float* bml    = (float*)alloc(128 * 4);
    float* eWihc  = (float*)alloc((size_t)L_ * G3_ * 4);
    float* dWihc  = (float*)alloc((size_t)L_ * G3_ * 4);
    float* z      = (float*)alloc((size_t)B_ * H_ * 4);
    float* wt     = (float*)alloc((size_t)L_ * B_ * W_ * 4);
    float* lq     = (float*)alloc((size_t)B_ * 4);
    float* lpz    = (float*)alloc((size_t)B_ * 4);
    float* lpx    = (float*)alloc((size_t)B_ * 4);
    float* lkl    = (float*)alloc((size_t)B_ * 4);
    float* bacc   = (float*)alloc((size_t)B_ * 4);

    const dim3 blk(256);
    const int nBH = B_ * H_;

    // ---- prep (2 launches) ----
    ConvJobs J;
    J.s[0] = x;    J.d[0] = xh;
    J.s[1] = Wf1;  J.d[1] = Wf1h;
    J.s[2] = eWhh; J.d[2] = eWhhh;
    J.s[3] = eWd;  J.d[3] = eWdh;
    J.s[4] = dWhh; J.d[4] = dWhhh;
    J.s[5] = dWd;  J.d[5] = dWdh;
    J.s[6] = dWo;  J.d[6] = dWoh;
    J.s[7] = Wr;   J.d[7] = Wrh;
    J.s[8] = Wmu;  J.d[8] = Wmlh;
    J.s[9] = Wlv;  J.d[9] = Wmlh + (long)Z_ * H_;
    conv_multi<<<(CJ_TOTAL / 8 + 255) / 256, blk, 0, stream>>>(J);
    prep_misc<<<4577, blk, 0, stream>>>(eWih, eWihh, dWih, dWihh, workers, wt,
                                        bacc, lpx, eWihc, dWihc, bmu, blv, bml);

    // ---- first cell: t[:,0] ----
    predict_head512<<<B_ / 32, blk, 0, stream>>>(xh, Wf1h, bf1, Wf2, bf2, t, L_);

    // ---- encoder scan ----
    _Float16* zcur = zb0;
    _Float16* znxt = zb1;
    for (int l = 0; l < L_; ++l) {
        if (l == 0)
            gru_fused<1, X_, 1><<<256, 512, 0, stream>>>(
                xh, eWihh, ebih, eWhhh, ebhh, eWihc, t, enc_eps, zcur, z, znxt);
        else
            gru_fused<1, X_, 0><<<256, 512, 0, stream>>>(
                xh, eWihh + (long)l * G3_ * X_, ebih + (long)l * G3_,
                eWhhh + (long)l * G3_ * H_, ebhh + (long)l * G3_,
                eWihc + (long)l * G3_, t + l, enc_eps + (long)l * nBH,
                zcur, z, znxt);
        _Float16* tmp = zcur; zcur = znxt; znxt = tmp;
        if (l < L_ - 1)
            predict_fast<<<B_ / 32, blk, 0, stream>>>(
                zcur, eWdh + (long)l * H_ * H_, ebd + (long)l * H_,
                eWo + (long)l * H_, ebo + l, t + (l + 1), L_);
    }

    // ---- latent (fused GEMM + elementwise) ----
    latent_fused<<<B_ / 32, blk, 0, stream>>>(zcur, Wmlh, bml, samp_eps, lath, lq, lpz);

    // ---- decoder scan ----
    zcur = zb0; znxt = zb1;
    for (int l = 0; l < L_; ++l) {
        if (l == 0)
            gru_fused<2, Z_, 1><<<256, 512, 0, stream>>>(
                lath, dWihh, dbih, dWhhh, dbhh, dWihc, t, dec_eps, zcur, z, znxt);
        else
            gru_fused<2, Z_, 0><<<256, 512, 0, stream>>>(
                lath, dWihh + (long)l * G3_ * Z_, dbih + (long)l * G3_,
                dWhhh + (long)l * G3_ * H_, dbhh + (long)l * G3_,
                dWihc + (long)l * G3_, t + l, dec_eps + (long)l * nBH,
                zcur, z, znxt);
        _Float16* tmp = zcur; zcur = znxt; znxt = tmp;
        dec_head_bce_fast<<<B_ / 32, blk, 0, stream>>>(
            zcur, dWdh + (long)l * H_ * H_, dbd + (long)l * H_,
            dWoh + (long)l * W_ * H_, dbo + (long)l * W_,
            wt + (long)l * B_ * W_, bacc);
    }

    // ---- recon + log_p_x fused ----
    recon_logpx_gemm<<<dim3(X_ / 128, B_ / 128), blk, 0, stream>>>(
        zcur, Wrh, br, x, lpx);
    // ---- KL ----
    kl_kernel<<<B_ / 256, blk, 0, stream>>>(t, workers, lkl);
    // ---- final loss ----
    final_reduce<<<1, 1024, 0, stream>>>(lq, lpz, bacc, lpx, lkl, loss);
}

// Round 14
// 1063.952 us; speedup vs baseline: 1.0114x; 1.0114x over previous
//
#include <hip/hip_runtime.h>
#include <hip/hip_bf16.h>
#include <math.h>

#define B_ 8192
#define X_ 512
#define H_ 256
#define Z_ 64
#define L_ 16
#define W_ 32
#define G3_ 768

#define STDF 1.0025031276057952f
#define CC 0.9189385332046727f

typedef _Float16 f16x8 __attribute__((ext_vector_type(8)));
typedef float f32x4 __attribute__((ext_vector_type(4)));

__device__ __forceinline__ float sigm(float x) { return 1.0f / (1.0f + expf(-x)); }
__device__ __forceinline__ float logsig(float u) {
    return (u > 0.0f) ? -log1pf(expf(-u)) : (u - log1pf(expf(u)));
}

#define GLOAD16(gsrc, ldst) \
    __builtin_amdgcn_global_load_lds((const __attribute__((address_space(1))) unsigned int*)(gsrc), \
                                     (__attribute__((address_space(3))) unsigned int*)(ldst), 16, 0, 0)

#define WAITV(N) asm volatile("s_waitcnt vmcnt(" #N ")" ::: "memory")
#define WAITV0() asm volatile("s_waitcnt vmcnt(0)" ::: "memory")
#define SBAR()  do { __builtin_amdgcn_sched_barrier(0); __builtin_amdgcn_s_barrier(); } while (0)

#define MFMA16(a, b, c) __builtin_amdgcn_mfma_f32_16x16x32_f16((a), (b), (c), 0, 0, 0)

// ------- fused GRU step, BM=128, 512 threads, grid 256 (2 blocks/CU) --------
// MODE 1: enc (t >= .5); MODE 2: dec (t > .5). KX = A2 inner dim.
template<int MODE, int KX, int FIRST>
__global__ __launch_bounds__(512) void gru_fused(
    const _Float16* __restrict__ A2,
    const _Float16* __restrict__ Wih,
    const float* __restrict__ bih,
    const _Float16* __restrict__ Whh,
    const float* __restrict__ bhh,
    const float* __restrict__ ec,
    const float* __restrict__ tcol,
    const float* __restrict__ eps,
    const _Float16* __restrict__ zh_in,
    float* __restrict__ z,
    _Float16* __restrict__ zh_out)
{
    constexpr int N1 = KX / 64;
    constexpr int NT = N1 + (FIRST ? 0 : 4);
    __shared__ char smem[2][(128 + 192) * 128];   // 80 KB

    const int tid  = threadIdx.x;
    const int wave = tid >> 6;
    const int lane = tid & 63;
    const int wr   = wave >> 1;          // 0..3: 32-row quarter
    const int wc   = wave & 1;           // 0..1: 32-col half per gate
    const int id   = blockIdx.x;
    const int xcd  = id & 7;
    const int wk   = id >> 3;            // 0..31
    const int bm   = (xcd * 8 + (wk >> 2)) * 128;
    const int h0   = (wk & 3) * 64;
    const int l15  = lane & 15;
    const int l4   = lane >> 4;

    f32x4 acc[2][6];
    f32x4 accN[2][2];
    #pragma unroll
    for (int a = 0; a < 2; ++a) {
        #pragma unroll
        for (int b = 0; b < 6; ++b) { f32x4 zz = {0.f,0.f,0.f,0.f}; acc[a][b] = zz; }
        #pragma unroll
        for (int b = 0; b < 2; ++b) { f32x4 zz = {0.f,0.f,0.f,0.f}; accN[a][b] = zz; }
    }

    auto stage = [&](int s, int pb) {
        char* As = smem[pb];
        char* Ws = smem[pb] + 128 * 128;
        const _Float16* srcA;
        const _Float16* srcW;
        int KA, k0;
        if (s < N1) { srcA = A2;    srcW = Wih; KA = KX;  k0 = s * 64; }
        else        { srcA = zh_in; srcW = Whh; KA = 256; k0 = (s - N1) * 64; }
        #pragma unroll
        for (int q = 0; q < 2; ++q) {
            int f   = q * 8192 + tid * 16;
            int row = f >> 7;
            int c   = ((f >> 4) & 7) ^ (row & 7);
            GLOAD16(srcA + (long)(bm + row) * KA + k0 + c * 8, As + f);
        }
        #pragma unroll
        for (int q = 0; q < 3; ++q) {
            int f   = q * 8192 + tid * 16;
            int rr  = f >> 7;
            int c   = ((f >> 4) & 7) ^ (rr & 7);
            int srow = (rr >> 6) * 256 + h0 + (rr & 63);
            GLOAD16(srcW + (long)srow * KA + k0 + c * 8, Ws + f);
        }
    };

    stage(0, 0);
    for (int s = 0; s < NT; ++s) {
        int pb = s & 1;
        if (s + 1 < NT) { stage(s + 1, pb ^ 1); WAITV(5); }
        else WAITV0();
        SBAR();
        char* As = smem[pb];
        char* Ws = smem[pb] + 128 * 128;
        bool p1 = (s < N1);
        #pragma unroll
        for (int ks = 0; ks < 2; ++ks) {
            f16x8 af[2], bf[6];
            #pragma unroll
            for (int mi = 0; mi < 2; ++mi) {
                int row = wr * 32 + mi * 16 + l15;
                int c   = (ks * 4 + l4) ^ (row & 7);
                af[mi] = *(const f16x8*)(As + row * 128 + c * 16);
            }
            #pragma unroll
            for (int ni = 0; ni < 6; ++ni) {
                int rr = (ni >> 1) * 64 + wc * 32 + (ni & 1) * 16 + l15;
                int c  = (ks * 4 + l4) ^ (rr & 7);
                bf[ni] = *(const f16x8*)(Ws + rr * 128 + c * 16);
            }
            if (p1) {
                #pragma unroll
                for (int mi = 0; mi < 2; ++mi) {
                    #pragma unroll
                    for (int ni = 0; ni < 4; ++ni)
                        acc[mi][ni] = MFMA16(af[mi], bf[ni], acc[mi][ni]);
                    #pragma unroll
                    for (int ni = 4; ni < 6; ++ni)
                        accN[mi][ni - 4] = MFMA16(af[mi], bf[ni], accN[mi][ni - 4]);
                }
            } else {
                #pragma unroll
                for (int mi = 0; mi < 2; ++mi)
                    #pragma unroll
                    for (int ni = 0; ni < 6; ++ni)
                        acc[mi][ni] = MFMA16(af[mi], bf[ni], acc[mi][ni]);
            }
        }
        SBAR();
    }

    #pragma unroll
    for (int mi = 0; mi < 2; ++mi)
        #pragma unroll
        for (int r = 0; r < 4; ++r) {
            int grow = bm + wr * 32 + mi * 16 + l4 * 4 + r;
            float tv = tcol[(long)grow * L_];
            float ext = (MODE == 1) ? (tv >= 0.5f ? 1.0f : 0.0f)
                                    : (tv >  0.5f ? 1.0f : 0.0f);
            #pragma unroll
            for (int hb = 0; hb < 2; ++hb) {
                int h = h0 + wc * 32 + hb * 16 + l15;
                float rpre = acc[mi][hb][r]     + bih[h]       + bhh[h]       + ext * ec[h];
                float zpre = acc[mi][2 + hb][r] + bih[256 + h] + bhh[256 + h] + ext * ec[256 + h];
                float hn   = acc[mi][4 + hb][r] + bhh[512 + h];
                float in_  = accN[mi][hb][r]    + bih[512 + h] + ext * ec[512 + h];
                float rg = sigm(rpre);
                float zt = sigm(zpre);
                float n  = tanhf(in_ + rg * hn);
                long zi = (long)grow * 256 + h;
                float zold = FIRST ? 0.0f : z[zi];
                float v = (1.0f - zt) * n + zt * zold + STDF * eps[zi];
                z[zi] = v;
                zh_out[zi] = (_Float16)v;
            }
        }
}

// ------- predict head K=512 (first cell), pipelined BM=32 -------------------
__global__ __launch_bounds__(256) void predict_head512(
    const _Float16* __restrict__ A,
    const _Float16* __restrict__ Wd,     // [256][512]
    const float* __restrict__ bd,
    const float* __restrict__ wo,
    const float* __restrict__ bo,
    float* __restrict__ out, int ostride)
{
    constexpr int K = 512;
    constexpr int NT = K / 64;
    __shared__ char smem[2][(32 + 256) * 128];
    __shared__ float part[32][4];

    const int tid  = threadIdx.x;
    const int wave = tid >> 6;
    const int lane = tid & 63;
    const int bm   = blockIdx.x * 32;
    const int l15  = lane & 15;
    const int l4   = lane >> 4;

    f32x4 acc[2][4];
    #pragma unroll
    for (int a = 0; a < 2; ++a)
        #pragma unroll
        for (int b = 0; b < 4; ++b) { f32x4 zz = {0.f,0.f,0.f,0.f}; acc[a][b] = zz; }

    auto stage = [&](int s, int pb) {
        char* As = smem[pb];
        char* Ws = smem[pb] + 32 * 128;
        int k0 = s * 64;
        {
            int o   = wave * 1024 + lane * 16;
            int row = o >> 7;
            int c   = ((o >> 4) & 7) ^ (row & 7);
            GLOAD16(A + (long)(bm + row) * K + k0 + c * 8, As + wave * 1024);
        }
        #pragma unroll
        for (int it = 0; it < 8; ++it) {
            int q   = it * 4 + wave;
            int o   = q * 1024 + lane * 16;
            int row = o >> 7;
            int c   = ((o >> 4) & 7) ^ (row & 7);
            GLOAD16(Wd + (long)row * K + k0 + c * 8, Ws + q * 1024);
        }
    };

    stage(0, 0);
    for (int s = 0; s < NT; ++s) {
        int pb = s & 1;
        if (s + 1 < NT) { stage(s + 1, pb ^ 1); WAITV(9); }
        else WAITV0();
        SBAR();
        char* As = smem[pb];
        char* Ws = smem[pb] + 32 * 128;
        #pragma unroll
        for (int ks = 0; ks < 2; ++ks) {
            f16x8 af[2], bf[4];
            #pragma unroll
            for (int mi = 0; mi < 2; ++mi) {
                int row = mi * 16 + l15;
                int c   = (ks * 4 + l4) ^ (row & 7);
                af[mi] = *(const f16x8*)(As + row * 128 + c * 16);
            }
            #pragma unroll
            for (int ni = 0; ni < 4; ++ni) {
                int row = wave * 64 + ni * 16 + l15;
                int c   = (ks * 4 + l4) ^ (row & 7);
                bf[ni] = *(const f16x8*)(Ws + row * 128 + c * 16);
            }
            #pragma unroll
            for (int mi = 0; mi < 2; ++mi)
                #pragma unroll
                for (int ni = 0; ni < 4; ++ni)
                    acc[mi][ni] = MFMA16(af[mi], bf[ni], acc[mi][ni]);
        }
        SBAR();
    }

    float bdv[4], wov[4];
    #pragma unroll
    for (int ni = 0; ni < 4; ++ni) {
        int col = wave * 64 + ni * 16 + l15;
        bdv[ni] = bd[col];
        wov[ni] = wo[col];
    }
    #pragma unroll
    for (int mi = 0; mi < 2; ++mi)
        #pragma unroll
        for (int r = 0; r < 4; ++r) {
            float s = 0.0f;
            #pragma unroll
            for (int ni = 0; ni < 4; ++ni) {
                float v = fmaxf(acc[mi][ni][r] + bdv[ni], 0.0f);
                s = fmaf(v, wov[ni], s);
            }
            #pragma unroll
            for (int off = 1; off < 16; off <<= 1) s += __shfl_xor(s, off, 16);
            if (l15 == 0) part[mi * 16 + l4 * 4 + r][wave] = s;
        }
    __syncthreads();
    if (tid < 32) {
        float u = part[tid][0] + part[tid][1] + part[tid][2] + part[tid][3] + bo[0];
        out[(long)(bm + tid) * ostride] = sigm(u);
    }
}

// ------- predict head K=256: full-W LDS, single stage -----------------------
__global__ __launch_bounds__(256) void predict_fast(
    const _Float16* __restrict__ A,
    const _Float16* __restrict__ Wd,     // [256][256]
    const float* __restrict__ bd,
    const float* __restrict__ wo,
    const float* __restrict__ bo,
    float* __restrict__ out, int ostride)
{
    __shared__ char Wl[131072];
    __shared__ char Al[16384];
    __shared__ float part[32][4];

    const int tid  = threadIdx.x;
    const int wave = tid >> 6;
    const int lane = tid & 63;
    const int bm   = blockIdx.x * 32;
    const int l15  = lane & 15;
    const int l4   = lane >> 4;

    #pragma unroll
    for (int q = 0; q < 32; ++q) {
        int f   = q * 4096 + tid * 16;
        int kc  = f >> 15;
        int o   = f & 32767;
        int row = o >> 7;
        int c   = ((o >> 4) & 7) ^ (row & 7);
        GLOAD16(Wd + (long)row * 256 + kc * 64 + c * 8, Wl + f);
    }
    #pragma unroll
    for (int q = 0; q < 4; ++q) {
        int f   = q * 4096 + tid * 16;
        int kc  = f >> 12;
        int o   = f & 4095;
        int row = o >> 7;
        int c   = ((o >> 4) & 7) ^ (row & 7);
        GLOAD16(A + (long)(bm + row) * 256 + kc * 64 + c * 8, Al + f);
    }
    WAITV0();
    __syncthreads();

    f32x4 acc[2][4];
    #pragma unroll
    for (int a = 0; a < 2; ++a)
        #pragma unroll
        for (int b = 0; b < 4; ++b) { f32x4 zz = {0.f,0.f,0.f,0.f}; acc[a][b] = zz; }

    #pragma unroll
    for (int kc = 0; kc < 4; ++kc)
        #pragma unroll
        for (int ks = 0; ks < 2; ++ks) {
            f16x8 af[2], bf[4];
            #pragma unroll
            for (int mi = 0; mi < 2; ++mi) {
                int row = mi * 16 + l15;
                int c   = (ks * 4 + l4) ^ (row & 7);
                af[mi] = *(const f16x8*)(Al + kc * 4096 + row * 128 + c * 16);
            }
            #pragma unroll
            for (int ni = 0; ni < 4; ++ni) {
                int row = wave * 64 + ni * 16 + l15;
                int c   = (ks * 4 + l4) ^ (row & 7);
                bf[ni] = *(const f16x8*)(Wl + kc * 32768 + row * 128 + c * 16);
            }
            #pragma unroll
            for (int mi = 0; mi < 2; ++mi)
                #pragma unroll
                for (int ni = 0; ni < 4; ++ni)
                    acc[mi][ni] = MFMA16(af[mi], bf[ni], acc[mi][ni]);
        }

    float bdv[4], wov[4];
    #pragma unroll
    for (int ni = 0; ni < 4; ++ni) {
        int col = wave * 64 + ni * 16 + l15;
        bdv[ni] = bd[col];
        wov[ni] = wo[col];
    }
    #pragma unroll
    for (int mi = 0; mi < 2; ++mi)
        #pragma unroll
        for (int r = 0; r < 4; ++r) {
            float s = 0.0f;
            #pragma unroll
            for (int ni = 0; ni < 4; ++ni) {
                float v = fmaxf(acc[mi][ni][r] + bdv[ni], 0.0f);
                s = fmaf(v, wov[ni], s);
            }
            #pragma unroll
            for (int off = 1; off < 16; off <<= 1) s += __shfl_xor(s, off, 16);
            if (l15 == 0) part[mi * 16 + l4 * 4 + r][wave] = s;
        }
    __syncthreads();
    if (tid < 32) {
        float u = part[tid][0] + part[tid][1] + part[tid][2] + part[tid][3] + bo[0];
        out[(long)(bm + tid) * ostride] = sigm(u);
    }
}

// ------- decoder head+BCE: full-Wd LDS single stage, A direct from L2 -------
__global__ __launch_bounds__(256) void dec_head_bce_fast(
    const _Float16* __restrict__ A,      // zh [B][256]
    const _Float16* __restrict__ Wd,     // [256][256]
    const float* __restrict__ bd,
    const _Float16* __restrict__ Wo,     // [32][256]
    const float* __restrict__ bo,
    const float* __restrict__ wt,        // [B][32]
    float* __restrict__ bacc)
{
    __shared__ char Wl[131072];
    __shared__ _Float16 ds[32 * 264];
    __shared__ float part[32][2];

    const int tid  = threadIdx.x;
    const int wave = tid >> 6;
    const int lane = tid & 63;
    const int bm   = blockIdx.x * 32;
    const int l15  = lane & 15;
    const int l4   = lane >> 4;

    #pragma unroll
    for (int q = 0; q < 32; ++q) {
        int f   = q * 4096 + tid * 16;
        int kc  = f >> 15;
        int o   = f & 32767;
        int row = o >> 7;
        int c   = ((o >> 4) & 7) ^ (row & 7);
        GLOAD16(Wd + (long)row * 256 + kc * 64 + c * 8, Wl + f);
    }
    f16x8 afr[8];
    #pragma unroll
    for (int kc = 0; kc < 4; ++kc)
        #pragma unroll
        for (int mi = 0; mi < 2; ++mi) {
            int row = mi * 16 + l15;
            afr[kc * 2 + mi] = *(const f16x8*)(A + (long)(bm + row) * 256 + kc * 64 + l4 * 8);
        }

    f32x4 acc[2][4];
    #pragma unroll
    for (int a = 0; a < 2; ++a)
        #pragma unroll
        for (int b = 0; b < 4; ++b) { f32x4 zz = {0.f,0.f,0.f,0.f}; acc[a][b] = zz; }

    WAITV0();
    __syncthreads();

    #pragma unroll
    for (int kc = 0; kc < 4; ++kc) {
        f16x8 bf[4];
        #pragma unroll
        for (int ni = 0; ni < 4; ++ni) {
            int row = wave * 64 + ni * 16 + l15;
            int c   = (0 * 4 + l4) ^ (row & 7);
            bf[ni] = *(const f16x8*)(Wl + kc * 32768 + row * 128 + c * 16);
        }
        #pragma unroll
        for (int mi = 0; mi < 2; ++mi)
            #pragma unroll
            for (int ni = 0; ni < 4; ++ni)
                acc[mi][ni] = MFMA16(afr[kc * 2 + mi], bf[ni], acc[mi][ni]);
    }
    #pragma unroll
    for (int kc = 0; kc < 4; ++kc)
        #pragma unroll
        for (int mi = 0; mi < 2; ++mi) {
            int row = mi * 16 + l15;
            afr[kc * 2 + mi] = *(const f16x8*)(A + (long)(bm + row) * 256 + kc * 64 + 32 + l4 * 8);
        }
    #pragma unroll
    for (int kc = 0; kc < 4; ++kc) {
        f16x8 bf[4];
        #pragma unroll
        for (int ni = 0; ni < 4; ++ni) {
            int row = wave * 64 + ni * 16 + l15;
            int c   = (1 * 4 + l4) ^ (row & 7);
            bf[ni] = *(const f16x8*)(Wl + kc * 32768 + row * 128 + c * 16);
        }
        #pragma unroll
        for (int mi = 0; mi < 2; ++mi)
            #pragma unroll
            for (int ni = 0; ni < 4; ++ni)
                acc[mi][ni] = MFMA16(afr[kc * 2 + mi], bf[ni], acc[mi][ni]);
    }

    #pragma unroll
    for (int mi = 0; mi < 2; ++mi)
        #pragma unroll
        for (int r = 0; r < 4; ++r) {
            int row = mi * 16 + l4 * 4 + r;
            #pragma unroll
            for (int ni = 0; ni < 4; ++ni) {
                int col = wave * 64 + ni * 16 + l15;
                ds[row * 264 + col] = (_Float16)fmaxf(acc[mi][ni][r] + bd[col], 0.0f);
            }
        }
    __syncthreads();

    const int rh = wave >> 1;
    const int ch = wave & 1;
    f32x4 acc2 = {0.f, 0.f, 0.f, 0.f};
    #pragma unroll
    for (int k = 0; k < 8; ++k) {
        f16x8 bf2 = *(const f16x8*)(Wo + (long)(ch * 16 + l15) * 256 + k * 32 + l4 * 8);
        f16x8 af  = *(const f16x8*)(ds + (rh * 16 + l15) * 264 + k * 32 + l4 * 8);
        acc2 = MFMA16(af, bf2, acc2);
    }

    #pragma unroll
    for (int r = 0; r < 4; ++r) {
        int row = rh * 16 + l4 * 4 + r;
        int w = ch * 16 + l15;
        float u = acc2[r] + bo[w];
        float logp   = fmaxf(logsig(u),  -100.0f);
        float log1mp = fmaxf(logsig(-u), -100.0f);
        float wk = wt[(long)(bm + row) * W_ + w];
        float s = -(wk * logp + (1.0f - wk) * log1mp);
        #pragma unroll
        for (int off = 1; off < 16; off <<= 1) s += __shfl_xor(s, off, 16);
        if (l15 == 0) part[row][ch] = s;
    }
    __syncthreads();
    if (tid < 32) bacc[bm + tid] += part[tid][0] + part[tid][1];
}

// ------- latent: full-Wml GEMM + softplus/sample/lq/lpz, fused --------------
__global__ __launch_bounds__(256) void latent_fused(
    const _Float16* __restrict__ A,      // zfin f16 [B][256]
    const _Float16* __restrict__ Wml,    // [128][256] (mu|lv rows)
    const float* __restrict__ bml,       // [128]
    const float* __restrict__ seps,
    _Float16* __restrict__ lath,
    float* __restrict__ lq, float* __restrict__ lpz)
{
    __shared__ char Wl[65536];
    __shared__ char Al[16384];
    __shared__ float muv[32][129];

    const int tid  = threadIdx.x;
    const int wave = tid >> 6;
    const int lane = tid & 63;
    const int bm   = blockIdx.x * 32;
    const int l15  = lane & 15;
    const int l4   = lane >> 4;

    #pragma unroll
    for (int q = 0; q < 16; ++q) {
        int f   = q * 4096 + tid * 16;
        int kc  = f >> 14;
        int o   = f & 16383;
        int row = o >> 7;
        int c   = ((o >> 4) & 7) ^ (row & 7);
        GLOAD16(Wml + (long)row * 256 + kc * 64 + c * 8, Wl + f);
    }
    #pragma unroll
    for (int q = 0; q < 4; ++q) {
        int f   = q * 4096 + tid * 16;
        int kc  = f >> 12;
        int o   = f & 4095;
        int row = o >> 7;
        int c   = ((o >> 4) & 7) ^ (row & 7);
        GLOAD16(A + (long)(bm + row) * 256 + kc * 64 + c * 8, Al + f);
    }
    WAITV0();
    __syncthreads();

    f32x4 acc[2][2];
    #pragma unroll
    for (int a = 0; a < 2; ++a)
        #pragma unroll
        for (int b = 0; b < 2; ++b) { f32x4 zz = {0.f,0.f,0.f,0.f}; acc[a][b] = zz; }

    #pragma unroll
    for (int kc = 0; kc < 4; ++kc)
        #pragma unroll
        for (int ks = 0; ks < 2; ++ks) {
            f16x8 af[2], bf[2];
            #pragma unroll
            for (int mi = 0; mi < 2; ++mi) {
                int row = mi * 16 + l15;
                int c   = (ks * 4 + l4) ^ (row & 7);
                af[mi] = *(const f16x8*)(Al + kc * 4096 + row * 128 + c * 16);
            }
            #pragma unroll
            for (int ni = 0; ni < 2; ++ni) {
                int row = wave * 32 + ni * 16 + l15;
                int c   = (ks * 4 + l4) ^ (row & 7);
                bf[ni] = *(const f16x8*)(Wl + kc * 16384 + row * 128 + c * 16);
            }
            #pragma unroll
            for (int mi = 0; mi < 2; ++mi)
                #pragma unroll
                for (int ni = 0; ni < 2; ++ni)
                    acc[mi][ni] = MFMA16(af[mi], bf[ni], acc[mi][ni]);
        }

    #pragma unroll
    for (int mi = 0; mi < 2; ++mi)
        #pragma unroll
        for (int r = 0; r < 4; ++r) {
            int row = mi * 16 + l4 * 4 + r;
            #pragma unroll
            for (int ni = 0; ni < 2; ++ni) {
                int col = wave * 32 + ni * 16 + l15;
                muv[row][col] = acc[mi][ni][r] + bml[col];
            }
        }
    __syncthreads();

    int rsub = lane >> 3;
    int row  = wave * 8 + rsub;
    int zlo  = lane & 7;
    float lpz_c = 0.0f, lq_c = 0.0f;
    #pragma unroll
    for (int j = 0; j < 8; ++j) {
        int zc = zlo * 8 + j;
        float mu = muv[row][zc];
        float sp = muv[row][64 + zc];
        float lv = (sp > 0.0f) ? (sp + log1pf(expf(-sp))) : log1pf(expf(sp));
        float e  = seps[(long)(bm + row) * Z_ + zc];
        float lat = mu + expf(0.5f * lv) * e;
        lath[(long)(bm + row) * Z_ + zc] = (_Float16)lat;
        lpz_c += -CC - 0.5f * lat * lat;
        float d = lat - mu;
        lq_c += -CC - 0.5f * lv - d * d / (2.0f * expf(lv));
    }
    #pragma unroll
    for (int off = 1; off < 8; off <<= 1) {
        lpz_c += __shfl_xor(lpz_c, off, 8);
        lq_c  += __shfl_xor(lq_c, off, 8);
    }
    if (zlo == 0) { lpz[bm + row] = lpz_c; lq[bm + row] = lq_c; }
}

// ------- recon GEMM (BM=128, BN=128) + log_p_x epilogue (atomic) ------------
__global__ __launch_bounds__(256) void recon_logpx_gemm(
    const _Float16* __restrict__ A,      // zh [B][256]
    const _Float16* __restrict__ Wt,     // [512][256]
    const float* __restrict__ bias,      // [512]
    const float* __restrict__ x,         // [B][512]
    float* __restrict__ lpx)
{
    constexpr int K = 256;
    constexpr int NT = 4;
    __shared__ char smem[2][(128 + 128) * 128];
    __shared__ float part[128][2];

    const int tid  = threadIdx.x;
    const int wave = tid >> 6;
    const int lane = tid & 63;
    const int wr   = wave >> 1;
    const int wc   = wave & 1;
    const int bm   = blockIdx.y * 128;
    const int bn   = blockIdx.x * 128;
    const int l15  = lane & 15;
    const int l4   = lane >> 4;

    f32x4 acc[4][4];
    #pragma unroll
    for (int a = 0; a < 4; ++a)
        #pragma unroll
        for (int b = 0; b < 4; ++b) { f32x4 zz = {0.f,0.f,0.f,0.f}; acc[a][b] = zz; }

    auto stage = [&](int s, int pb) {
        char* As = smem[pb];
        char* Ws = smem[pb] + 128 * 128;
        int k0 = s * 64;
        #pragma unroll
        for (int it = 0; it < 4; ++it) {
            int q   = it * 4 + wave;
            int o   = q * 1024 + lane * 16;
            int row = o >> 7;
            int c   = ((o >> 4) & 7) ^ (row & 7);
            GLOAD16(A + (long)(bm + row) * K + k0 + c * 8, As + q * 1024);
        }
        #pragma unroll
        for (int it = 0; it < 4; ++it) {
            int q   = it * 4 + wave;
            int o   = q * 1024 + lane * 16;
            int row = o >> 7;
            int c   = ((o >> 4) & 7) ^ (row & 7);
            GLOAD16(Wt + (long)(bn + row) * K + k0 + c * 8, Ws + q * 1024);
        }
    };

    stage(0, 0);
    for (int s = 0; s < NT; ++s) {
        int pb = s & 1;
        if (s + 1 < NT) { stage(s + 1, pb ^ 1); WAITV(8); }
        else WAITV0();
        SBAR();
        char* As = smem[pb];
        char* Ws = smem[pb] + 128 * 128;
        #pragma unroll
        for (int ks = 0; ks < 2; ++ks) {
            f16x8 af[4], bf[4];
            #pragma unroll
            for (int mi = 0; mi < 4; ++mi) {
                int row = wr * 64 + mi * 16 + l15;
                int c   = (ks * 4 + l4) ^ (row & 7);
                af[mi] = *(const f16x8*)(As + row * 128 + c * 16);
            }
            #pragma unroll
            for (int ni = 0; ni < 4; ++ni) {
                int row = wc * 64 + ni * 16 + l15;
                int c   = (ks * 4 + l4) ^ (row & 7);
                bf[ni] = *(const f16x8*)(Ws + row * 128 + c * 16);
            }
            #pragma unroll
            for (int mi = 0; mi < 4; ++mi)
                #pragma unroll
                for (int ni = 0; ni < 4; ++ni)
                    acc[mi][ni] = MFMA16(af[mi], bf[ni], acc[mi][ni]);
        }
        SBAR();
    }

    #pragma unroll
    for (int mi = 0; mi < 4; ++mi)
        #pragma unroll
        for (int r = 0; r < 4; ++r) {
            int grow = bm + wr * 64 + mi * 16 + l4 * 4 + r;
            float s = 0.0f;
            #pragma unroll
            for (int ni = 0; ni < 4; ++ni) {
                int gcol = bn + wc * 64 + ni * 16 + l15;
                float u = acc[mi][ni][r] + bias[gcol];
                s = fmaf(x[(long)grow * X_ + gcol], logsig(u), s);
            }
            #pragma unroll
            for (int off = 1; off < 16; off <<= 1) s += __shfl_xor(s, off, 16);
            if (l15 == 0) part[wr * 64 + mi * 16 + l4 * 4 + r][wc] = s;
        }
    __syncthreads();
    if (tid < 128) atomicAdd(&lpx[bm + tid], part[tid][0] + part[tid][1]);
}

// ---------------- fused contiguous f32->f16 conversions ---------------------
struct ConvJobs {
    const float* s[10];
    _Float16* d[10];
};
__device__ __constant__ const long CJ_CNT[10] = {
    (long)B_ * X_, (long)H_ * X_, (long)L_ * G3_ * H_, (long)L_ * H_ * H_,
    (long)L_ * G3_ * H_, (long)L_ * H_ * H_, (long)L_ * W_ * H_,
    (long)X_ * H_, (long)Z_ * H_, (long)Z_ * H_
};
#define CJ_TOTAL 13008896L

__global__ __launch_bounds__(256) void conv_multi(ConvJobs J)
{
    long i8 = ((long)blockIdx.x * 256 + threadIdx.x) * 8;
    if (i8 >= CJ_TOTAL) return;
    long rem = i8; int j = 0;
    #pragma unroll
    for (int k = 0; k < 9; ++k)
        if (rem >= CJ_CNT[k]) { rem -= CJ_CNT[k]; ++j; } else break;
    const float* s = J.s[j] + rem;
    f16x8 o;
    #pragma unroll
    for (int q = 0; q < 8; ++q) o[q] = (_Float16)s[q];
    *(f16x8*)(J.d[j] + rem) = o;
}

// strided convs + extracts + bias-stack + wtrans (+zero bacc/lpx), one kernel
__global__ __launch_bounds__(256) void prep_misc(
    const float* __restrict__ eWih, _Float16* __restrict__ eWihh,
    const float* __restrict__ dWih, _Float16* __restrict__ dWihh,
    const float* __restrict__ workers, float* __restrict__ wt,
    float* __restrict__ bacc, float* __restrict__ lpx,
    float* __restrict__ eWihc, float* __restrict__ dWihc,
    const float* __restrict__ bmu, const float* __restrict__ blv,
    float* __restrict__ bml)
{
    int blk = blockIdx.x;
    int tid = threadIdx.x;
    if (blk < 3072) {                       // eWih: [12288][513] -> [12288][512] f16
        long i = ((long)blk * 256 + tid) * 8;
        long r = i >> 9, k = i & 511;
        const float* s = eWih + r * 513 + k;
        f16x8 o;
        #pragma unroll
        for (int q = 0; q < 8; ++q) o[q] = (_Float16)s[q];
        *(f16x8*)(eWihh + i) = o;
    } else if (blk < 3456) {                // dWih: [12288][65] -> [12288][64] f16
        long i = ((long)(blk - 3072) * 256 + tid) * 8;
        long r = i >> 6, k = i & 63;
        const float* s = dWih + r * 65 + k;
        f16x8 o;
        #pragma unroll
        for (int q = 0; q < 8; ++q) o[q] = (_Float16)s[q];
        *(f16x8*)(dWihh + i) = o;
    } else if (blk < 4480) {                // wtrans + zero bacc/lpx
        long idx = (long)(blk - 3456) * 256 + tid;
        int w = idx & 31;
        long b = idx >> 5;
        const float* src = workers + (w * (long)B_ + b) * L_;
        #pragma unroll
        for (int l = 0; l < L_; ++l)
            wt[((long)l * B_ + b) * W_ + w] = src[l];
        if (w == 0) { bacc[b] = 0.0f; lpx[b] = 0.0f; }
    } else if (blk < 4528) {                // extract eWih col 512
        int i = (blk - 4480) * 256 + tid;
        if (i < L_ * G3_) eWihc[i] = eWih[(long)i * 513 + 512];
    } else if (blk < 4576) {                // extract dWih col 64
        int i = (blk - 4528) * 256 + tid;
        if (i < L_ * G3_) dWihc[i] = dWih[(long)i * 65 + 64];
    } else {                                // stack bias
        if (tid < 128) bml[tid] = (tid < 64) ? bmu[tid] : blv[tid - 64];
    }
}

// ---------------- KL term ---------------------------------------------------
__global__ __launch_bounds__(256) void kl_kernel(
    const float* __restrict__ tmat, const float* __restrict__ workers,
    float* __restrict__ lkl)
{
    int b = blockIdx.x * 256 + threadIdx.x;
    float wb[L_];
    #pragma unroll
    for (int l = 0; l < L_; ++l) wb[l] = 0.0f;
    for (int w = 0; w < W_; ++w) {
        const float* p = workers + ((long)w * B_ + b) * L_;
        #pragma unroll
        for (int l = 0; l < L_; ++l) wb[l] += p[l];
    }
    float s = 0.0f;
    #pragma unroll
    for (int l = 0; l < L_; ++l) {
        float wbar = wb[l] * (1.0f / 32.0f);
        float tv = tmat[(long)b * L_ + l];
        s += tv * (logf(tv + 1e-6f) - logf(wbar + 1e-6f));
    }
    lkl[b] = s;
}

// ---------------- final reduction ------------------------------------------
__global__ __launch_bounds__(1024) void final_reduce(
    const float* __restrict__ lq, const float* __restrict__ lpz,
    const float* __restrict__ bacc, const float* __restrict__ lpx,
    const float* __restrict__ lkl, float* __restrict__ out)
{
    __shared__ float red[16];
    float s = 0.0f;
    for (int b = threadIdx.x; b < B_; b += 1024)
        s += lq[b] - lpz[b] + bacc[b] - lpx[b] + lkl[b];
    #pragma unroll
    for (int off = 32; off; off >>= 1) s += __shfl_down(s, off);
    int wave = threadIdx.x >> 6, lane = threadIdx.x & 63;
    if (lane == 0) red[wave] = s;
    __syncthreads();
    if (threadIdx.x == 0) {
        float t = 0.0f;
        for (int i = 0; i < 16; ++i) t += red[i];
        out[0] = t / (float)B_;
    }
}

extern "C" void kernel_launch(void* const* d_in, const int* in_sizes, int n_in,
                              void* d_out, int out_size, void* d_ws, size_t ws_size,
                              hipStream_t stream)
{
    const float* x       = (const float*)d_in[0];
    const float* workers = (const float*)d_in[1];
    const float* Wf1     = (const float*)d_in[2];
    const float* bf1     = (const float*)d_in[3];
    const float* Wf2     = (const float*)d_in[4];
    const float* bf2     = (const float*)d_in[5];
    const float* eWih    = (const float*)d_in[6];
    const float* eWhh    = (const float*)d_in[7];
    const float* ebih    = (const float*)d_in[8];
    const float* ebhh    = (const float*)d_in[9];
    const float* eWd     = (const float*)d_in[10];
    const float* ebd     = (const float*)d_in[11];
    const float* eWo     = (const float*)d_in[12];
    const float* ebo     = (const float*)d_in[13];
    const float* Wmu     = (const float*)d_in[14];
    const float* bmu     = (const float*)d_in[15];
    const float* Wlv     = (const float*)d_in[16];
    const float* blv     = (const float*)d_in[17];
    const float* dWih    = (const float*)d_in[18];
    const float* dWhh    = (const float*)d_in[19];
    const float* dbih    = (const float*)d_in[20];
    const float* dbhh    = (const float*)d_in[21];
    const float* dWd     = (const float*)d_in[22];
    const float* dbd     = (const float*)d_in[23];
    const float* dWo     = (const float*)d_in[24];
    const float* dbo     = (const float*)d_in[25];
    const float* Wr      = (const float*)d_in[26];
    const float* br      = (const float*)d_in[27];
    const float* enc_eps = (const float*)d_in[28];
    const float* samp_eps= (const float*)d_in[29];
    const float* dec_eps = (const float*)d_in[30];

    float* t    = (float*)d_out;
    float* loss = t + (long)B_ * L_;

    char* p = (char*)d_ws;
    auto alloc = [&](size_t bytes) {
        char* r = p;
        p += (bytes + 255) & ~(size_t)255;
        return r;
    };
    _Float16* xh    = (_Float16*)alloc((size_t)B_ * X_ * 2);
    _Float16* zb0   = (_Float16*)alloc((size_t)B_ * H_ * 2);
    _Float16* zb1   = (_Float16*)alloc((size_t)B_ * H_ * 2);
    _Float16* lath  = (_Float16*)alloc((size_t)B_ * Z_ * 2);
    _Float16* Wf1h  = (_Float16*)alloc((size_t)H_ * X_ * 2);
    _Float16* eWihh = (_Float16*)alloc((size_t)L_ * G3_ * X_ * 2);
    _Float16* eWhhh = (_Float16*)alloc((size_t)L_ * G3_ * H_ * 2);
    _Float16* eWdh  = (_Float16*)alloc((size_t)L_ * H_ * H_ * 2);
    _Float16* dWihh = (_Float16*)alloc((size_t)L_ * G3_ * Z_ * 2);
    _Float16* dWhhh = (_Float16*)alloc((size_t)L_ * G3_ * H_ * 2);
    _Float16* dWdh  = (_Float16*)alloc((size_t)L_ * H_ * H_ * 2);
    _Float16* dWoh  = (_Float16*)alloc((size_t)L_ * W_ * H_ * 2);
    _Float16* Wrh   = (_Float16*)alloc((size_t)X_ * H_ * 2);
    _Float16* Wmlh  = (_Float16*)alloc((size_t)128 * H_ * 2);
    float* bml    = (float*)alloc(128 * 4);
    float* eWihc  = (float*)alloc((size_t)L_ * G3_ * 4);
    float* dWihc  = (float*)alloc((size_t)L_ * G3_ * 4);
    float* z      = (float*)alloc((size_t)B_ * H_ * 4);
    float* wt     = (float*)alloc((size_t)L_ * B_ * W_ * 4);
    float* lq     = (float*)alloc((size_t)B_ * 4);
    float* lpz    = (float*)alloc((size_t)B_ * 4);
    float* lpx    = (float*)alloc((size_t)B_ * 4);
    float* lkl    = (float*)alloc((size_t)B_ * 4);
    float* bacc   = (float*)alloc((size_t)B_ * 4);

    const dim3 blk(256);
    const int nBH = B_ * H_;

    // ---- prep (2 launches) ----
    ConvJobs J;
    J.s[0] = x;    J.d[0] = xh;
    J.s[1] = Wf1;  J.d[1] = Wf1h;
    J.s[2] = eWhh; J.d[2] = eWhhh;
    J.s[3] = eWd;  J.d[3] = eWdh;
    J.s[4] = dWhh; J.d[4] = dWhhh;
    J.s[5] = dWd;  J.d[5] = dWdh;
    J.s[6] = dWo;  J.d[6] = dWoh;
    J.s[7] = Wr;   J.d[7] = Wrh;
    J.s[8] = Wmu;  J.d[8] = Wmlh;
    J.s[9] = Wlv;  J.d[9] = Wmlh + (long)Z_ * H_;
    conv_multi<<<(CJ_TOTAL / 8 + 255) / 256, blk, 0, stream>>>(J);
    prep_misc<<<4577, blk, 0, stream>>>(eWih, eWihh, dWih, dWihh, workers, wt,
                                        bacc, lpx, eWihc, dWihc, bmu, blv, bml);

    // ---- first cell: t[:,0] ----
    predict_head512<<<B_ / 32, blk, 0, stream>>>(xh, Wf1h, bf1, Wf2, bf2, t, L_);

    // ---- encoder scan ----
    _Float16* zcur = zb0;
    _Float16* znxt = zb1;
    for (int l = 0; l < L_; ++l) {
        if (l == 0)
            gru_fused<1, X_, 1><<<256, 512, 0, stream>>>(
                xh, eWihh, ebih, eWhhh, ebhh, eWihc, t, enc_eps, zcur, z, znxt);
        else
            gru_fused<1, X_, 0><<<256, 512, 0, stream>>>(
                xh, eWihh + (long)l * G3_ * X_, ebih + (long)l * G3_,
                eWhhh + (long)l * G3_ * H_, ebhh + (long)l * G3_,
                eWihc + (long)l * G3_, t + l, enc_eps + (long)l * nBH,
                zcur, z, znxt);
        _Float16* tmp = zcur; zcur = znxt; znxt = tmp;
        if (l < L_ - 1)
            predict_fast<<<B_ / 32, blk, 0, stream>>>(
                zcur, eWdh + (long)l * H_ * H_, ebd + (long)l * H_,
                eWo + (long)l * H_, ebo + l, t + (l + 1), L_);
    }

    // ---- latent (fused GEMM + elementwise) ----
    latent_fused<<<B_ / 32, blk, 0, stream>>>(zcur, Wmlh, bml, samp_eps, lath, lq, lpz);

    // ---- decoder scan ----
    zcur = zb0; znxt = zb1;
    for (int l = 0; l < L_; ++l) {
        if (l == 0)
            gru_fused<2, Z_, 1><<<256, 512, 0, stream>>>(
                lath, dWihh, dbih, dWhhh, dbhh, dWihc, t, dec_eps, zcur, z, znxt);
        else
            gru_fused<2, Z_, 0><<<256, 512, 0, stream>>>(
                lath, dWihh + (long)l * G3_ * Z_, dbih + (long)l * G3_,
                dWhhh + (long)l * G3_ * H_, dbhh + (long)l * G3_,
                dWihc + (long)l * G3_, t + l, dec_eps + (long)l * nBH,
                zcur, z, znxt);
        _Float16* tmp = zcur; zcur = znxt; znxt = tmp;
        dec_head_bce_fast<<<B_ / 32, blk, 0, stream>>>(
            zcur, dWdh + (long)l * H_ * H_, dbd + (long)l * H_,
            dWoh + (long)l * W_ * H_, dbo + (long)l * W_,
            wt + (long)l * B_ * W_, bacc);
    }

    // ---- recon + log_p_x fused ----
    recon_logpx_gemm<<<dim3(X_ / 128, B_ / 128), blk, 0, stream>>>(
        zcur, Wrh, br, x, lpx);
    // ---- KL ----
    kl_kernel<<<B_ / 256, blk, 0, stream>>>(t, workers, lkl);
    // ---- final loss ----
    final_reduce<<<1, 1024, 0, stream>>>(lq, lpz, bacc, lpx, lkl, loss);
}